// Round 3
// baseline (220.330 us; speedup 1.0000x reference)
//
#include <hip/hip_runtime.h>
#include <math.h>

// ROIAlign FPN, sample-major layout.
// Block = one (n, c): 256 threads = 16x16 padded sample grid (14x14 active).
// Each thread computes one bilinear sample (4 taps), then 2x2 adaptive max
// pool via shfl_xor(1) (sx pair) and shfl_xor(16) (sy pair within wave).
// Grid = 1024 * 256 = 262144 blocks.

__global__ __launch_bounds__(256) void roialign_sample_kernel(
    const float* __restrict__ f0, const float* __restrict__ f1,
    const float* __restrict__ f2, const float* __restrict__ f3,
    const float* __restrict__ props, float* __restrict__ out)
{
    const int blk = blockIdx.x;      // n*256 + c
    const int c   = blk & 255;
    const int n   = blk >> 8;        // 0..1023
    const int b   = n >> 9;          // image 0..1

    const int tid = threadIdx.x;
    const int sx  = tid & 15;        // sample col 0..15 (14 active)
    const int sy  = tid >> 4;        // sample row 0..15 (14 active)
    const float rx = (float)min(sx, 13);
    const float ry = (float)min(sy, 13);

    // proposal (block-uniform -> scalar path)
    const float px1 = props[n * 4 + 0];
    const float py1 = props[n * 4 + 1];
    const float px2 = props[n * 4 + 2];
    const float py2 = props[n * 4 + 3];
    const float area = (px2 - px1) * (py2 - py1);
    float lf = floorf(2.0f + log2f(sqrtf(area) / 224.0f));
    lf = fminf(fmaxf(lf, 0.0f), 3.0f);
    const int lvl = (int)lf;

    const float* feat;
    int W;
    float scale;
    if (lvl == 0)      { feat = f0; W = 256; scale = 0.25f;    }
    else if (lvl == 1) { feat = f1; W = 128; scale = 0.125f;   }
    else if (lvl == 2) { feat = f2; W = 64;  scale = 0.0625f;  }
    else               { feat = f3; W = 32;  scale = 0.03125f; }

    // scaled proposal + sampling units (exact same expressions as round 1)
    const float sx1f = px1 * scale;
    const float sy1f = py1 * scale;
    const float sx2f = px2 * scale;
    const float sy2f = py2 * scale;
    const float w_unit = (sx2f - sx1f) / 14.0f;
    const float h_unit = (sy2f - sy1f) / 14.0f;
    const float Wm1 = (float)(W - 1);

    // x geometry for this sample
    const float fx = rx * w_unit + w_unit * 0.5f + sx1f;
    int x0 = (int)floorf(fx);
    const float xc = fminf(fmaxf(fx, 0.0f), Wm1);
    int x0c = min(max(x0, 0), W - 1);
    int x1c = min(max(x0 + 1, 0), W - 1);
    const float wx0 = (float)x1c - xc;   // weight for column x0c
    const float wx1 = xc - (float)x0c;   // weight for column x1c
    const int xv = min(x0c, W - 2);      // load [xv], [xv+1]; valid because
                                         // whenever x0c==W-1 both weights are 0

    // y geometry
    const float fy = ry * h_unit + h_unit * 0.5f + sy1f;
    int y0 = (int)floorf(fy);
    const float yc = fminf(fmaxf(fy, 0.0f), Wm1);
    int y0c = min(max(y0, 0), W - 1);
    int y1c = min(max(y0 + 1, 0), W - 1);
    const float wy0 = (float)y1c - yc;
    const float wy1 = yc - (float)y0c;

    const float* fb  = feat + ((size_t)b * 256 + (size_t)c) * (size_t)(W * W);
    const float* r0  = fb + (size_t)y0c * (size_t)W;
    const float* r1  = fb + (size_t)y1c * (size_t)W;

    const float a0 = r0[xv];
    const float a1 = r0[xv + 1];
    const float b0 = r1[xv];
    const float b1 = r1[xv + 1];

    // bilinear (weights-from-clipped-coords semantics incl. boundary zeroing)
    float v = wx0 * (wy0 * a0 + wy1 * b0) + wx1 * (wy0 * a1 + wy1 * b1);

    // 2x2 adaptive max pool across lanes
    v = fmaxf(v, __shfl_xor(v, 1));    // sx pair (2pw, 2pw+1)
    v = fmaxf(v, __shfl_xor(v, 16));   // sy pair (2ph, 2ph+1)

    if (((sx | sy) & 1) == 0 && sx < 14 && sy < 14) {
        out[(size_t)blk * 49 + (size_t)(sy >> 1) * 7 + (size_t)(sx >> 1)] = v;
    }
}

extern "C" void kernel_launch(void* const* d_in, const int* in_sizes, int n_in,
                              void* d_out, int out_size, void* d_ws, size_t ws_size,
                              hipStream_t stream) {
    const float* f0 = (const float*)d_in[0];
    const float* f1 = (const float*)d_in[1];
    const float* f2 = (const float*)d_in[2];
    const float* f3 = (const float*)d_in[3];
    const float* props = (const float*)d_in[4];
    float* out = (float*)d_out;

    dim3 grid(1024 * 256), block(256);
    hipLaunchKernelGGL(roialign_sample_kernel, grid, block, 0, stream,
                       f0, f1, f2, f3, props, out);
}

// Round 6
// 75.360 us; speedup vs baseline: 2.9237x; 2.9237x over previous
//
#include <hip/hip_runtime.h>
#include <math.h>

// ROIAlign FPN, channel-loop layout.
// Block = (proposal n, channel-quarter cs): 256 threads = 16x16 padded sample
// grid (14x14 active). Geometry computed ONCE per thread, then a 64-channel
// loop does only 4 gathers + bilinear + shfl-pool + predicated store.
// Grid = 1024 * 4 = 4096 blocks.

#define CSPLIT 4
#define CPB (256 / CSPLIT)   // channels per block = 64

__global__ __launch_bounds__(256) void roialign_chan_kernel(
    const float* __restrict__ f0, const float* __restrict__ f1,
    const float* __restrict__ f2, const float* __restrict__ f3,
    const float* __restrict__ props, float* __restrict__ out)
{
    const int blk = blockIdx.x;          // n*CSPLIT + cs
    const int cs  = blk & (CSPLIT - 1);
    const int n   = blk >> 2;            // 0..1023
    const int b   = n >> 9;              // image 0..1

    const int tid = threadIdx.x;
    const int sx  = tid & 15;            // sample col 0..15 (14 active)
    const int sy  = tid >> 4;            // sample row 0..15 (14 active)
    const float rx = (float)min(sx, 13);
    const float ry = (float)min(sy, 13);

    // proposal (block-uniform -> scalar path)
    const float px1 = props[n * 4 + 0];
    const float py1 = props[n * 4 + 1];
    const float px2 = props[n * 4 + 2];
    const float py2 = props[n * 4 + 3];
    const float area = (px2 - px1) * (py2 - py1);
    float lf = floorf(2.0f + log2f(sqrtf(area) / 224.0f));
    lf = fminf(fmaxf(lf, 0.0f), 3.0f);
    const int lvl = (int)lf;

    const float* feat;
    int W;
    float scale;
    if (lvl == 0)      { feat = f0; W = 256; scale = 0.25f;    }
    else if (lvl == 1) { feat = f1; W = 128; scale = 0.125f;   }
    else if (lvl == 2) { feat = f2; W = 64;  scale = 0.0625f;  }
    else               { feat = f3; W = 32;  scale = 0.03125f; }

    // scaled proposal + sampling units (identical expressions to round 1/2)
    const float sx1f = px1 * scale;
    const float sy1f = py1 * scale;
    const float sx2f = px2 * scale;
    const float sy2f = py2 * scale;
    const float w_unit = (sx2f - sx1f) / 14.0f;
    const float h_unit = (sy2f - sy1f) / 14.0f;
    const float Wm1 = (float)(W - 1);

    // x geometry
    const float fx = rx * w_unit + w_unit * 0.5f + sx1f;
    int x0 = (int)floorf(fx);
    const float xc = fminf(fmaxf(fx, 0.0f), Wm1);
    int x0c = min(max(x0, 0), W - 1);
    int x1c = min(max(x0 + 1, 0), W - 1);
    const float wx0 = (float)x1c - xc;
    const float wx1 = xc - (float)x0c;
    const int xv = min(x0c, W - 2);      // when x0c==W-1 both weights are 0

    // y geometry
    const float fy = ry * h_unit + h_unit * 0.5f + sy1f;
    int y0 = (int)floorf(fy);
    const float yc = fminf(fmaxf(fy, 0.0f), Wm1);
    int y0c = min(max(y0, 0), W - 1);
    int y1c = min(max(y0 + 1, 0), W - 1);
    const float wy0 = (float)y1c - yc;
    const float wy1 = yc - (float)y0c;

    // per-lane tap offsets (channel-invariant), 32-bit
    const int off00 = y0c * W + xv;      // row y0c, col xv / xv+1
    const int off10 = y1c * W + xv;      // row y1c
    const int WW = W * W;

    const int c0 = cs * CPB;
    const float* fb = feat + ((size_t)b * 256 + (size_t)c0) * (size_t)WW;

    const bool active = (((sx | sy) & 1) == 0) && sx < 14 && sy < 14;
    float* outp = out + (size_t)(n * 256 + c0) * 49
                      + (size_t)(sy >> 1) * 7 + (size_t)(sx >> 1);

    #pragma unroll 4
    for (int c = 0; c < CPB; ++c) {
        const float* p = fb + (size_t)c * (size_t)WW;
        const float a0 = p[off00];
        const float a1 = p[off00 + 1];
        const float b0 = p[off10];
        const float b1 = p[off10 + 1];

        float v = wx0 * (wy0 * a0 + wy1 * b0) + wx1 * (wy0 * a1 + wy1 * b1);

        v = fmaxf(v, __shfl_xor(v, 1));    // sx pair
        v = fmaxf(v, __shfl_xor(v, 16));   // sy pair

        if (active) outp[(size_t)c * 49] = v;
    }
}

extern "C" void kernel_launch(void* const* d_in, const int* in_sizes, int n_in,
                              void* d_out, int out_size, void* d_ws, size_t ws_size,
                              hipStream_t stream) {
    const float* f0 = (const float*)d_in[0];
    const float* f1 = (const float*)d_in[1];
    const float* f2 = (const float*)d_in[2];
    const float* f3 = (const float*)d_in[3];
    const float* props = (const float*)d_in[4];
    float* out = (float*)d_out;

    dim3 grid(1024 * CSPLIT), block(256);
    hipLaunchKernelGGL(roialign_chan_kernel, grid, block, 0, stream,
                       f0, f1, f2, f3, props, out);
}

// Round 7
// 75.256 us; speedup vs baseline: 2.9277x; 1.0014x over previous
//
#include <hip/hip_runtime.h>
#include <math.h>

// ROIAlign FPN, channel-loop layout + float2 x-pair taps.
// Block = (proposal n, channel-quarter cs): 256 threads = 16x16 padded sample
// grid (14x14 active). Geometry computed ONCE per thread, then a 64-channel
// loop does 2 float2 gathers (row y0c, row y1c) + bilinear + shfl-pool +
// predicated store. Grid = 1024 * 4 = 4096 blocks.
// The float2 loads are 4B-aligned only (xv arbitrary); CDNA global memory
// supports unaligned vector access, and xv+1 <= W-1 keeps them in-bounds.

#define CSPLIT 4
#define CPB (256 / CSPLIT)   // channels per block = 64

__global__ __launch_bounds__(256) void roialign_chan_kernel(
    const float* __restrict__ f0, const float* __restrict__ f1,
    const float* __restrict__ f2, const float* __restrict__ f3,
    const float* __restrict__ props, float* __restrict__ out)
{
    const int blk = blockIdx.x;          // n*CSPLIT + cs
    const int cs  = blk & (CSPLIT - 1);
    const int n   = blk >> 2;            // 0..1023
    const int b   = n >> 9;              // image 0..1

    const int tid = threadIdx.x;
    const int sx  = tid & 15;            // sample col 0..15 (14 active)
    const int sy  = tid >> 4;            // sample row 0..15 (14 active)
    const float rx = (float)min(sx, 13);
    const float ry = (float)min(sy, 13);

    // proposal (block-uniform -> scalar path)
    const float px1 = props[n * 4 + 0];
    const float py1 = props[n * 4 + 1];
    const float px2 = props[n * 4 + 2];
    const float py2 = props[n * 4 + 3];
    const float area = (px2 - px1) * (py2 - py1);
    float lf = floorf(2.0f + log2f(sqrtf(area) / 224.0f));
    lf = fminf(fmaxf(lf, 0.0f), 3.0f);
    const int lvl = (int)lf;

    const float* feat;
    int W;
    float scale;
    if (lvl == 0)      { feat = f0; W = 256; scale = 0.25f;    }
    else if (lvl == 1) { feat = f1; W = 128; scale = 0.125f;   }
    else if (lvl == 2) { feat = f2; W = 64;  scale = 0.0625f;  }
    else               { feat = f3; W = 32;  scale = 0.03125f; }

    // scaled proposal + sampling units (identical expressions to prior rounds)
    const float sx1f = px1 * scale;
    const float sy1f = py1 * scale;
    const float sx2f = px2 * scale;
    const float sy2f = py2 * scale;
    const float w_unit = (sx2f - sx1f) / 14.0f;
    const float h_unit = (sy2f - sy1f) / 14.0f;
    const float Wm1 = (float)(W - 1);

    // x geometry
    const float fx = rx * w_unit + w_unit * 0.5f + sx1f;
    int x0 = (int)floorf(fx);
    const float xc = fminf(fmaxf(fx, 0.0f), Wm1);
    int x0c = min(max(x0, 0), W - 1);
    int x1c = min(max(x0 + 1, 0), W - 1);
    const float wx0 = (float)x1c - xc;
    const float wx1 = xc - (float)x0c;
    const int xv = min(x0c, W - 2);      // when x0c==W-1 both weights are 0

    // y geometry
    const float fy = ry * h_unit + h_unit * 0.5f + sy1f;
    int y0 = (int)floorf(fy);
    const float yc = fminf(fmaxf(fy, 0.0f), Wm1);
    int y0c = min(max(y0, 0), W - 1);
    int y1c = min(max(y0 + 1, 0), W - 1);
    const float wy0 = (float)y1c - yc;
    const float wy1 = yc - (float)y0c;

    // per-lane tap offsets (channel-invariant), 32-bit
    const int off00 = y0c * W + xv;      // row y0c, cols xv, xv+1
    const int off10 = y1c * W + xv;      // row y1c
    const int WW = W * W;

    const int c0 = cs * CPB;
    const float* fb = feat + ((size_t)b * 256 + (size_t)c0) * (size_t)WW;

    const bool active = (((sx | sy) & 1) == 0) && sx < 14 && sy < 14;
    float* outp = out + (size_t)(n * 256 + c0) * 49
                      + (size_t)(sy >> 1) * 7 + (size_t)(sx >> 1);

    #pragma unroll 4
    for (int c = 0; c < CPB; ++c) {
        const float* p = fb + (size_t)c * (size_t)WW;
        const float2 a = *reinterpret_cast<const float2*>(p + off00);
        const float2 bb = *reinterpret_cast<const float2*>(p + off10);

        float v = wy0 * (wx0 * a.x + wx1 * a.y)
                + wy1 * (wx0 * bb.x + wx1 * bb.y);

        v = fmaxf(v, __shfl_xor(v, 1));    // sx pair
        v = fmaxf(v, __shfl_xor(v, 16));   // sy pair

        if (active) outp[(size_t)c * 49] = v;
    }
}

extern "C" void kernel_launch(void* const* d_in, const int* in_sizes, int n_in,
                              void* d_out, int out_size, void* d_ws, size_t ws_size,
                              hipStream_t stream) {
    const float* f0 = (const float*)d_in[0];
    const float* f1 = (const float*)d_in[1];
    const float* f2 = (const float*)d_in[2];
    const float* f3 = (const float*)d_in[3];
    const float* props = (const float*)d_in[4];
    float* out = (float*)d_out;

    dim3 grid(1024 * CSPLIT), block(256);
    hipLaunchKernelGGL(roialign_chan_kernel, grid, block, 0, stream,
                       f0, f1, f2, f3, props, out);
}